// Round 5
// baseline (713.314 us; speedup 1.0000x reference)
//
#include <hip/hip_runtime.h>
#include <hip/hip_bf16.h>
#include <cstddef>

// Problem constants
#define NB 256   // batch
#define RR 32    // rooms
#define WW 8     // room width
#define HH 6     // room height
#define MXY 72   // map extent
#define EMB 6
#define CIN1 16  // 9 + 1 + 6

typedef __bf16 bf16x8 __attribute__((ext_vector_type(8)));
typedef float floatx4 __attribute__((ext_vector_type(4)));

// --- Workspace layout (byte offsets) ---------------------------------------
// conv weight fragments (bf16/short), packed in exact B-frag order
static const size_t B_W1F  = 0;         // 16 ksteps * 4096 B = 65536 (taps>=25 zero)
static const size_t B_W2F  = 65536;     // 18 * 4096 = 73728
static const size_t B_W3F  = 139264;    // 73728 -> ends 212992
static const size_t B_HEAD = 212992;    // fp32 head weights, 122880 floats = 491520 B
//   float offsets inside HEAD:
static const size_t F_WR1T = 0;         // (64,128)    8192
static const size_t F_WR2T = 8192;      // (128,128)  16384
static const size_t F_F1T  = 24576;     // (128,256)  32768
static const size_t F_F2T  = 57344;     // (256,256)  65536 -> 122880 floats
static const size_t B_FEAT = 704512;    // (256,32,64) f32 = 2097152 B
static const size_t B_CHUNK = 2801664;  // per-chunk activation buffers
// per-image bytes: X bf16 5184*16*2=165888 ; Y bf16 5184*64*2=663552 (x2)
static const size_t PERN_BYTES = 165888 + 2 * 663552;  // 1492992

__device__ inline short f2b(float f) {
    unsigned u = __builtin_bit_cast(unsigned, f);
    unsigned r = (u + 0x7fffu + ((u >> 16) & 1u)) >> 16;
    return (short)r;
}
__device__ inline float b2f(short s) {
    unsigned u = ((unsigned)(unsigned short)s) << 16;
    return __builtin_bit_cast(float, u);
}

// ---------------------------------------------------------------------------
// Prep: conv weights fp32 -> bf16 B-fragment order; head weights transposed.
// Fragment order: [kk][ntile][lane][j] ; virtual k = kk*32 + (lane>>4)*8 + j
// oc = ntile*16 + (lane&15) ; (tap, ci) = (k / CIN, k % CIN)
// ---------------------------------------------------------------------------
__global__ void prep_weights(const float* __restrict__ w1, const float* __restrict__ w2,
                             const float* __restrict__ w3, const float* __restrict__ wr1,
                             const float* __restrict__ wr2, const float* __restrict__ wf1,
                             const float* __restrict__ wf2, char* __restrict__ ws)
{
    short* W1F = (short*)(ws + B_W1F);
    short* W2F = (short*)(ws + B_W2F);
    short* W3F = (short*)(ws + B_W3F);
    float* HEAD = (float*)(ws + B_HEAD);

    int idx = blockIdx.x * 256 + threadIdx.x;
    if (idx < 32768) {  // conv1: 16 ksteps (padded), CIN=16, taps 0..24 real
        int j = idx & 7, lane = (idx >> 3) & 63, nt = (idx >> 9) & 3, kk = idx >> 11;
        int k = kk * 32 + (lane >> 4) * 8 + j;
        int oc = nt * 16 + (lane & 15);
        int tap = k >> 4, ci = k & 15;
        float v = (tap < 25) ? w1[(oc * 16 + ci) * 25 + tap] : 0.f;
        W1F[idx] = f2b(v);
        return;
    }
    idx -= 32768;
    if (idx < 36864) {  // conv2: 18 ksteps, CIN=64, 9 taps
        int j = idx & 7, lane = (idx >> 3) & 63, nt = (idx >> 9) & 3, kk = idx >> 11;
        int k = kk * 32 + (lane >> 4) * 8 + j;
        int oc = nt * 16 + (lane & 15);
        int tap = k >> 6, ci = k & 63;
        W2F[idx] = f2b(w2[(oc * 64 + ci) * 9 + tap]);
        return;
    }
    idx -= 36864;
    if (idx < 36864) {  // conv3
        int j = idx & 7, lane = (idx >> 3) & 63, nt = (idx >> 9) & 3, kk = idx >> 11;
        int k = kk * 32 + (lane >> 4) * 8 + j;
        int oc = nt * 16 + (lane & 15);
        int tap = k >> 6, ci = k & 63;
        W3F[idx] = f2b(w3[(oc * 64 + ci) * 9 + tap]);
        return;
    }
    idx -= 36864;
    if (idx < 8192)  { int o = idx & 127, c = idx >> 7; HEAD[F_WR1T + idx] = wr1[o * 64 + c]; return; }
    idx -= 8192;
    if (idx < 16384) { int o = idx & 127, c = idx >> 7; HEAD[F_WR2T + idx] = wr2[o * 128 + c]; return; }
    idx -= 16384;
    if (idx < 32768) { int o = idx & 255, c = idx >> 8; HEAD[F_F1T + idx] = wf1[o * 128 + c]; return; }
    idx -= 32768;
    if (idx < 65536) { int o = idx & 255, c = idx >> 8; HEAD[F_F2T + idx] = wf2[o * 256 + c]; return; }
}

// ---------------------------------------------------------------------------
// Build X (nc, 72, 72, 16) NHWC bf16: scatter room tensors + embedding, ch9=1
// One block per sample; rooms serialized via syncthreads (no atomics).
// ---------------------------------------------------------------------------
__global__ __launch_bounds__(256) void build_x(const int* __restrict__ pos,
                                               const float* __restrict__ rt,
                                               const float* __restrict__ emb,
                                               short* __restrict__ X, int n0)
{
    const int nl = blockIdx.x;
    const int n = n0 + nl;
    const int tid = threadIdx.x;
    short* Xn = X + (size_t)nl * (MXY * MXY) * CIN1;

    const short ONE = 0x3F80;  // bf16 1.0
    for (int i = tid; i < MXY * MXY * CIN1; i += 256)
        Xn[i] = ((i & 15) == 9) ? ONE : (short)0;
    __syncthreads();

    for (int r = 0; r < RR; ++r) {
        int px = pos[(n * RR + r) * 2 + 0];
        int py = pos[(n * RR + r) * 2 + 1];
        for (int i = tid; i < 15 * WW * HH; i += 256) {
            int c15 = i / 48;
            int j = i - c15 * 48;       // w*6 + h
            int w = j / 6, h = j - w * 6;
            float v; int c;
            if (c15 < 9) { v = rt[(r * 9 + c15) * 48 + j]; c = c15; }
            else { v = emb[r * EMB + (c15 - 9)] * rt[(r * 9 + 0) * 48 + j]; c = c15 + 1; }
            size_t a = ((size_t)(px + w) * MXY + (py + h)) * CIN1 + c;
            Xn[a] = f2b(b2f(Xn[a]) + v);
        }
        __syncthreads();
    }
}

// ---------------------------------------------------------------------------
// MFMA conv + bias + ReLU, NHWC bf16. Block = 3 waves, tile 8x24 px, 64 oc.
// Wave tile: 64 px (4 m-tiles) x 64 oc (4 n-tiles), 16x16x32 bf16 MFMA.
// Weights live in registers (B frags straight from L2, ping-pong, CHUNK=2).
// Reg budget: 64 acc (AGPR) + 64 B + 16 A + ~20 misc ~= 165 <= 170
//   -> 3 waves/SIMD via __launch_bounds__(192,3); LDS 37.9KB -> 4 blocks/CU.
// (Round 4 at CHUNK=3 was 176 regs -> 2 waves/SIMD -> occupancy-capped.)
// K-loop has no barriers; only wave-local vmcnt/lgkm waits.
// ---------------------------------------------------------------------------
template <int CIN, int K, int NKP, int CHUNK, int CIP>
__global__ __launch_bounds__(192, 3) void conv_mfma(const short* __restrict__ in,
                                                    const short* __restrict__ wF,
                                                    const float* __restrict__ bias,
                                                    short* __restrict__ out)
{
    constexpr int PAD = K / 2;
    constexpr int TR = 8 + K - 1;
    constexpr int TC = 24 + K - 1;
    constexpr int CG = CIN / 8;
    constexpr int NC = NKP / CHUNK;            // number of K chunks

    __shared__ __align__(16) short s_in[TR * TC * CIP];

    const int tid = threadIdx.x;
    const int lane = tid & 63;
    const int wv = tid >> 6;
    const int ml = lane & 15;
    const int q = lane >> 4;
    const int n = blockIdx.y;
    const int x0 = (blockIdx.x / 3) * 8;
    const int y0 = (blockIdx.x % 3) * 24;

    const short* inn = in + (size_t)n * (MXY * MXY) * CIN;

    // B-fragment register ping-pong: [buf][kstep-in-chunk][ntile]
    bf16x8 Bbuf[2][CHUNK][4];
    auto load_chunk = [&](int c, bf16x8 (*dst)[4]) {
        const short* src = wF + (size_t)c * CHUNK * 2048;
#pragma unroll
        for (int kl = 0; kl < CHUNK; ++kl)
#pragma unroll
            for (int j2 = 0; j2 < 4; ++j2)
                dst[kl][j2] = *reinterpret_cast<const bf16x8*>(
                    src + kl * 2048 + (j2 * 64 + lane) * 8);
    };

    load_chunk(0, Bbuf[0]);

    // --- stage input tile (zero-padded halo), 16B per thread-iteration ---
    for (int i = tid; i < TR * TC * CG; i += 192) {
        int cg = i % CG;
        int pix = i / CG;
        int r = pix / TC, c = pix - r * TC;
        int gx = x0 - PAD + r, gy = y0 - PAD + c;
        uint4 v = make_uint4(0u, 0u, 0u, 0u);
        if ((unsigned)gx < (unsigned)MXY && (unsigned)gy < (unsigned)MXY)
            v = *reinterpret_cast<const uint4*>(inn + ((size_t)gx * MXY + gy) * CIN + cg * 8);
        *reinterpret_cast<uint4*>(&s_in[pix * CIP + cg * 8]) = v;
    }
    __syncthreads();  // the ONLY barrier before the epilogue

    // per-lane pixel coords for A fragments (4 m-tiles of 16 pixels)
    int prow[4], pcol[4];
#pragma unroll
    for (int i = 0; i < 4; ++i) {
        int p = wv * 64 + i * 16 + ml;
        prow[i] = p / 24;
        pcol[i] = p - prow[i] * 24;
    }

    floatx4 acc[4][4] = {};

#pragma unroll
    for (int c = 0; c < NC; ++c) {
        // prefetch next weight chunk into the other register buffer;
        // 32 MFMAs below + cross-wave overlap (3 waves/SIMD) cover L2 latency
        if (c + 1 < NC) load_chunk(c + 1, Bbuf[(c + 1) & 1]);

#pragma unroll
        for (int kl = 0; kl < CHUNK; ++kl) {
            const int kk = c * CHUNK + kl;

            int tap, chb;
            if (CIN == 16) {  // conv1: kstep spans taps 2kk, 2kk+1 (tap>=25 weights are 0)
                tap = kk * 2 + (q >> 1);
                if (tap > 24) tap = 24;
                chb = (q & 1) * 8;
            } else {          // conv2/3: kstep = half of one tap's 64 channels
                tap = kk >> 1;
                chb = (kk & 1) * 32 + q * 8;
            }
            const int dx = tap / K, dy = tap - dx * K;

            bf16x8 A[4];
#pragma unroll
            for (int i = 0; i < 4; ++i)
                A[i] = *reinterpret_cast<const bf16x8*>(
                    &s_in[((prow[i] + dx) * TC + (pcol[i] + dy)) * CIP + chb]);

#pragma unroll
            for (int i = 0; i < 4; ++i)
#pragma unroll
                for (int j2 = 0; j2 < 4; ++j2)
                    acc[i][j2] = __builtin_amdgcn_mfma_f32_16x16x32_bf16(
                        A[i], Bbuf[c & 1][kl][j2], acc[i][j2], 0, 0, 0);
        }
    }

    // --- epilogue: bias + relu, bf16 NHWC stores ---
    float b4[4];
#pragma unroll
    for (int j2 = 0; j2 < 4; ++j2) b4[j2] = bias[j2 * 16 + ml];

    short* outn = out + (size_t)n * (MXY * MXY) * 64;
#pragma unroll
    for (int i = 0; i < 4; ++i) {
#pragma unroll
        for (int r = 0; r < 4; ++r) {
            int p = wv * 64 + i * 16 + q * 4 + r;
            int row = p / 24, col = p - row * 24;
            size_t base = ((size_t)(x0 + row) * MXY + (y0 + col)) * 64;
#pragma unroll
            for (int j2 = 0; j2 < 4; ++j2) {
                float v = acc[i][j2][r] + b4[j2];
                outn[base + j2 * 16 + ml] = f2b(fmaxf(v, 0.f));
            }
        }
    }
}

// ---------------------------------------------------------------------------
// Masked gather + mean over room footprint: feat[n][r][c] (fp32 out)
// One wave per (room, sample); lane = channel (coalesced bf16 NHWC reads).
// ---------------------------------------------------------------------------
__global__ void gather_mean(const short* __restrict__ Y, const float* __restrict__ rt,
                            const int* __restrict__ pos, float* __restrict__ feat, int n0)
{
    const int r = blockIdx.x;
    const int nl = blockIdx.y;
    const int n = n0 + nl;
    const int c = threadIdx.x;  // 64
    const int px = pos[(n * RR + r) * 2 + 0];
    const int py = pos[(n * RR + r) * 2 + 1];
    const short* y = Y + (size_t)nl * (MXY * MXY) * 64;
    const float* m = rt + r * 9 * 48;   // channel 0 = room_map

    float s = 0.f, ms = 0.f;
    for (int w = 0; w < WW; ++w)
        for (int h = 0; h < HH; ++h) {
            float mv = m[w * HH + h];
            ms += mv;
            if (mv != 0.f)
                s += mv * b2f(y[((size_t)(px + w) * MXY + (py + h)) * 64 + c]);
        }
    feat[((size_t)n * RR + r) * 64 + c] = s / ms;
}

// ---------------------------------------------------------------------------
// Per-sample head: room MLP (64->128->128), room-sum, fc1 (128->256), fc2
// ---------------------------------------------------------------------------
__global__ __launch_bounds__(256) void mlp_head(const float* __restrict__ feat,
                                                const float* __restrict__ HEAD,
                                                const float* __restrict__ b1,
                                                const float* __restrict__ b2,
                                                const float* __restrict__ bf1,
                                                const float* __restrict__ bf2,
                                                float* __restrict__ outp)
{
    __shared__ __align__(16) float s_feat[RR * 64];
    __shared__ __align__(16) float s_h1[RR * 128];
    __shared__ __align__(16) float s_s[2 * 128];
    __shared__ __align__(16) float s_sf[128];
    __shared__ __align__(16) float s_t1[256];

    const int n = blockIdx.x;
    const int tid = threadIdx.x;
    const float* W1t = HEAD + F_WR1T;
    const float* W2t = HEAD + F_WR2T;
    const float* F1t = HEAD + F_F1T;
    const float* F2t = HEAD + F_F2T;

    for (int i = tid; i < RR * 64; i += 256) s_feat[i] = feat[(size_t)n * RR * 64 + i];
    __syncthreads();

    const int o = tid & 127;
    const int rh = tid >> 7;

    float acc[16];
#pragma unroll
    for (int r = 0; r < 16; ++r) acc[r] = b1[o];
    for (int c4 = 0; c4 < 16; ++c4) {
        float w0 = W1t[(c4 * 4 + 0) * 128 + o];
        float w1 = W1t[(c4 * 4 + 1) * 128 + o];
        float w2 = W1t[(c4 * 4 + 2) * 128 + o];
        float w3 = W1t[(c4 * 4 + 3) * 128 + o];
#pragma unroll
        for (int r = 0; r < 16; ++r) {
            float4 f = *reinterpret_cast<const float4*>(&s_feat[(rh * 16 + r) * 64 + c4 * 4]);
            acc[r] += f.x * w0 + f.y * w1 + f.z * w2 + f.w * w3;
        }
    }
#pragma unroll
    for (int r = 0; r < 16; ++r) s_h1[(rh * 16 + r) * 128 + o] = fmaxf(acc[r], 0.f);
    __syncthreads();

#pragma unroll
    for (int r = 0; r < 16; ++r) acc[r] = b2[o];
    for (int c4 = 0; c4 < 32; ++c4) {
        float w0 = W2t[(c4 * 4 + 0) * 128 + o];
        float w1 = W2t[(c4 * 4 + 1) * 128 + o];
        float w2 = W2t[(c4 * 4 + 2) * 128 + o];
        float w3 = W2t[(c4 * 4 + 3) * 128 + o];
#pragma unroll
        for (int r = 0; r < 16; ++r) {
            float4 f = *reinterpret_cast<const float4*>(&s_h1[(rh * 16 + r) * 128 + c4 * 4]);
            acc[r] += f.x * w0 + f.y * w1 + f.z * w2 + f.w * w3;
        }
    }
    float ps = 0.f;
#pragma unroll
    for (int r = 0; r < 16; ++r) ps += fmaxf(acc[r], 0.f);
    s_s[rh * 128 + o] = ps;
    __syncthreads();
    if (tid < 128) s_sf[tid] = s_s[tid] + s_s[128 + tid];
    __syncthreads();

    {
        float a = bf1[tid];
        for (int c4 = 0; c4 < 32; ++c4) {
            float4 f = *reinterpret_cast<const float4*>(&s_sf[c4 * 4]);
            a += f.x * F1t[(c4 * 4 + 0) * 256 + tid];
            a += f.y * F1t[(c4 * 4 + 1) * 256 + tid];
            a += f.z * F1t[(c4 * 4 + 2) * 256 + tid];
            a += f.w * F1t[(c4 * 4 + 3) * 256 + tid];
        }
        s_t1[tid] = fmaxf(a, 0.f);
    }
    __syncthreads();

    {
        float a = bf2[tid];
        for (int c4 = 0; c4 < 64; ++c4) {
            float4 f = *reinterpret_cast<const float4*>(&s_t1[c4 * 4]);
            a += f.x * F2t[(c4 * 4 + 0) * 256 + tid];
            a += f.y * F2t[(c4 * 4 + 1) * 256 + tid];
            a += f.z * F2t[(c4 * 4 + 2) * 256 + tid];
            a += f.w * F2t[(c4 * 4 + 3) * 256 + tid];
        }
        outp[(size_t)n * 256 + tid] = a;
    }
}

// ---------------------------------------------------------------------------
extern "C" void kernel_launch(void* const* d_in, const int* in_sizes, int n_in,
                              void* d_out, int out_size, void* d_ws, size_t ws_size,
                              hipStream_t stream)
{
    const int* pos = (const int*)d_in[0];
    const float* rt = (const float*)d_in[1];
    const float* emb = (const float*)d_in[2];
    const float* w1 = (const float*)d_in[3];
    const float* bc1 = (const float*)d_in[4];
    const float* w2 = (const float*)d_in[5];
    const float* bc2 = (const float*)d_in[6];
    const float* w3 = (const float*)d_in[7];
    const float* bc3 = (const float*)d_in[8];
    const float* wr1 = (const float*)d_in[9];
    const float* br1 = (const float*)d_in[10];
    const float* wr2 = (const float*)d_in[11];
    const float* br2 = (const float*)d_in[12];
    const float* wf1 = (const float*)d_in[13];
    const float* bf1 = (const float*)d_in[14];
    const float* wf2 = (const float*)d_in[15];
    const float* bf2 = (const float*)d_in[16];
    float* out = (float*)d_out;
    char* ws = (char*)d_ws;

    prep_weights<<<896, 256, 0, stream>>>(w1, w2, w3, wr1, wr2, wf1, wf2, ws);

    // pick largest batch chunk that fits the workspace
    int nc = 16;
    const int cands[4] = {256, 128, 64, 32};
    for (int k = 0; k < 4; ++k) {
        size_t need = B_CHUNK + (size_t)cands[k] * PERN_BYTES;
        if (need <= ws_size) { nc = cands[k]; break; }
    }

    short* W1F = (short*)(ws + B_W1F);
    short* W2F = (short*)(ws + B_W2F);
    short* W3F = (short*)(ws + B_W3F);
    float* HEAD = (float*)(ws + B_HEAD);
    float* FEAT = (float*)(ws + B_FEAT);
    short* Xc = (short*)(ws + B_CHUNK);
    short* YA = Xc + (size_t)nc * (MXY * MXY) * CIN1;
    short* YB = YA + (size_t)nc * (MXY * MXY) * 64;

    for (int n0 = 0; n0 < NB; n0 += nc) {
        build_x<<<nc, 256, 0, stream>>>(pos, rt, emb, Xc, n0);
        conv_mfma<16, 5, 16, 2, 24><<<dim3(27, nc), 192, 0, stream>>>(Xc, W1F, bc1, YA);
        conv_mfma<64, 3, 18, 2, 72><<<dim3(27, nc), 192, 0, stream>>>(YA, W2F, bc2, YB);
        conv_mfma<64, 3, 18, 2, 72><<<dim3(27, nc), 192, 0, stream>>>(YB, W3F, bc3, YA);
        gather_mean<<<dim3(RR, nc), 64, 0, stream>>>(YA, rt, pos, FEAT, n0);
    }

    mlp_head<<<NB, 256, 0, stream>>>(FEAT, HEAD, br1, br2, bf1, bf2, out);
}

// Round 6
// 610.053 us; speedup vs baseline: 1.1693x; 1.1693x over previous
//
#include <hip/hip_runtime.h>
#include <hip/hip_bf16.h>
#include <cstddef>

// Problem constants
#define NB 256   // batch
#define RR 32    // rooms
#define WW 8     // room width
#define HH 6     // room height
#define MXY 72   // map extent
#define EMB 6
#define CIN1 16  // 9 + 1 + 6

typedef __bf16 bf16x8 __attribute__((ext_vector_type(8)));
typedef float floatx4 __attribute__((ext_vector_type(4)));

// --- Workspace layout (byte offsets) ---------------------------------------
// conv weight fragments (bf16/short), packed in exact B-frag order
static const size_t B_W1F  = 0;         // 14 ksteps * 4096 B = 57344 (taps>=25 zero)
static const size_t B_W2F  = 57344;     // 18 * 4096 = 73728
static const size_t B_W3F  = 131072;    // 73728 -> ends 204800
static const size_t B_HEAD = 204800;    // fp32 head weights, 122880 floats = 491520 B
//   float offsets inside HEAD:
static const size_t F_WR1T = 0;         // (64,128)    8192
static const size_t F_WR2T = 8192;      // (128,128)  16384
static const size_t F_F1T  = 24576;     // (128,256)  32768
static const size_t F_F2T  = 57344;     // (256,256)  65536 -> 122880 floats
static const size_t B_FEAT = 696320;    // (256,32,64) f32 = 2097152 B
static const size_t B_CHUNK = 2793472;  // per-chunk activation buffers
// per-image bytes: X bf16 5184*16*2=165888 ; Y bf16 5184*64*2=663552 (x2)
static const size_t PERN_BYTES = 165888 + 2 * 663552;  // 1492992

__device__ inline short f2b(float f) {
    unsigned u = __builtin_bit_cast(unsigned, f);
    unsigned r = (u + 0x7fffu + ((u >> 16) & 1u)) >> 16;
    return (short)r;
}
__device__ inline float b2f(short s) {
    unsigned u = ((unsigned)(unsigned short)s) << 16;
    return __builtin_bit_cast(float, u);
}

// ---------------------------------------------------------------------------
// Prep: conv weights fp32 -> bf16 B-fragment order; head weights transposed.
// Fragment order: [kk][ntile][lane][j] ; virtual k = kk*32 + (lane>>4)*8 + j
// oc = ntile*16 + (lane&15) ; (tap, ci) = (k / CIN, k % CIN)
// ---------------------------------------------------------------------------
__global__ void prep_weights(const float* __restrict__ w1, const float* __restrict__ w2,
                             const float* __restrict__ w3, const float* __restrict__ wr1,
                             const float* __restrict__ wr2, const float* __restrict__ wf1,
                             const float* __restrict__ wf2, char* __restrict__ ws)
{
    short* W1F = (short*)(ws + B_W1F);
    short* W2F = (short*)(ws + B_W2F);
    short* W3F = (short*)(ws + B_W3F);
    float* HEAD = (float*)(ws + B_HEAD);

    int idx = blockIdx.x * 256 + threadIdx.x;
    if (idx < 28672) {  // conv1: 14 ksteps (padded), CIN=16, taps 0..24 real
        int j = idx & 7, lane = (idx >> 3) & 63, nt = (idx >> 9) & 3, kk = idx >> 11;
        int k = kk * 32 + (lane >> 4) * 8 + j;
        int oc = nt * 16 + (lane & 15);
        int tap = k >> 4, ci = k & 15;
        float v = (tap < 25) ? w1[(oc * 16 + ci) * 25 + tap] : 0.f;
        W1F[idx] = f2b(v);
        return;
    }
    idx -= 28672;
    if (idx < 36864) {  // conv2: 18 ksteps, CIN=64, 9 taps
        int j = idx & 7, lane = (idx >> 3) & 63, nt = (idx >> 9) & 3, kk = idx >> 11;
        int k = kk * 32 + (lane >> 4) * 8 + j;
        int oc = nt * 16 + (lane & 15);
        int tap = k >> 6, ci = k & 63;
        W2F[idx] = f2b(w2[(oc * 64 + ci) * 9 + tap]);
        return;
    }
    idx -= 36864;
    if (idx < 36864) {  // conv3
        int j = idx & 7, lane = (idx >> 3) & 63, nt = (idx >> 9) & 3, kk = idx >> 11;
        int k = kk * 32 + (lane >> 4) * 8 + j;
        int oc = nt * 16 + (lane & 15);
        int tap = k >> 6, ci = k & 63;
        W3F[idx] = f2b(w3[(oc * 64 + ci) * 9 + tap]);
        return;
    }
    idx -= 36864;
    if (idx < 8192)  { int o = idx & 127, c = idx >> 7; HEAD[F_WR1T + idx] = wr1[o * 64 + c]; return; }
    idx -= 8192;
    if (idx < 16384) { int o = idx & 127, c = idx >> 7; HEAD[F_WR2T + idx] = wr2[o * 128 + c]; return; }
    idx -= 16384;
    if (idx < 32768) { int o = idx & 255, c = idx >> 8; HEAD[F_F1T + idx] = wf1[o * 128 + c]; return; }
    idx -= 32768;
    if (idx < 65536) { int o = idx & 255, c = idx >> 8; HEAD[F_F2T + idx] = wf2[o * 256 + c]; return; }
}

// ---------------------------------------------------------------------------
// Build X (nc, 72, 72, 16) NHWC bf16: scatter room tensors + embedding, ch9=1
// One block per sample; rooms serialized via syncthreads (no atomics).
// ---------------------------------------------------------------------------
__global__ __launch_bounds__(256) void build_x(const int* __restrict__ pos,
                                               const float* __restrict__ rt,
                                               const float* __restrict__ emb,
                                               short* __restrict__ X, int n0)
{
    const int nl = blockIdx.x;
    const int n = n0 + nl;
    const int tid = threadIdx.x;
    short* Xn = X + (size_t)nl * (MXY * MXY) * CIN1;

    const short ONE = 0x3F80;  // bf16 1.0
    for (int i = tid; i < MXY * MXY * CIN1; i += 256)
        Xn[i] = ((i & 15) == 9) ? ONE : (short)0;
    __syncthreads();

    for (int r = 0; r < RR; ++r) {
        int px = pos[(n * RR + r) * 2 + 0];
        int py = pos[(n * RR + r) * 2 + 1];
        for (int i = tid; i < 15 * WW * HH; i += 256) {
            int c15 = i / 48;
            int j = i - c15 * 48;       // w*6 + h
            int w = j / 6, h = j - w * 6;
            float v; int c;
            if (c15 < 9) { v = rt[(r * 9 + c15) * 48 + j]; c = c15; }
            else { v = emb[r * EMB + (c15 - 9)] * rt[(r * 9 + 0) * 48 + j]; c = c15 + 1; }
            size_t a = ((size_t)(px + w) * MXY + (py + h)) * CIN1 + c;
            Xn[a] = f2b(b2f(Xn[a]) + v);
        }
        __syncthreads();
    }
}

// ---------------------------------------------------------------------------
// MFMA conv + bias + ReLU, NHWC bf16. Block = 3 waves, tile 8x24 px, 64 oc.
// Wave tile: 64 px (4 m-tiles) x 64 oc (4 n-tiles), 16x16x32 bf16 MFMA.
// Weights live in registers (B frags straight from L2, ping-pong, CHUNK=2).
// Natural footprint ~= 64 acc (AGPR) + 64 B + 16 A + ~10 misc ~= 154 total
// -> HW derives 3 waves/SIMD from usage. DO NOT force min-waves=3: round 5
// showed the allocator spills the B buffer under that bound (WRITE_SIZE
// 83->182 MB). launch_bounds(192,2) is a cap only.
// K-loop has no barriers; only wave-local vmcnt/lgkm waits.
// ---------------------------------------------------------------------------
template <int CIN, int K, int NKP, int CHUNK, int CIP>
__global__ __launch_bounds__(192, 2) void conv_mfma(const short* __restrict__ in,
                                                    const short* __restrict__ wF,
                                                    const float* __restrict__ bias,
                                                    short* __restrict__ out)
{
    constexpr int PAD = K / 2;
    constexpr int TR = 8 + K - 1;
    constexpr int TC = 24 + K - 1;
    constexpr int CG = CIN / 8;
    constexpr int NC = NKP / CHUNK;            // number of K chunks

    __shared__ __align__(16) short s_in[TR * TC * CIP];

    const int tid = threadIdx.x;
    const int lane = tid & 63;
    const int wv = tid >> 6;
    const int ml = lane & 15;
    const int q = lane >> 4;
    const int n = blockIdx.y;
    const int x0 = (blockIdx.x / 3) * 8;
    const int y0 = (blockIdx.x % 3) * 24;

    const short* inn = in + (size_t)n * (MXY * MXY) * CIN;

    // B-fragment register ping-pong: [buf][kstep-in-chunk][ntile]
    bf16x8 Bbuf[2][CHUNK][4];
    auto load_chunk = [&](int c, bf16x8 (*dst)[4]) {
        const short* src = wF + (size_t)c * CHUNK * 2048;
#pragma unroll
        for (int kl = 0; kl < CHUNK; ++kl)
#pragma unroll
            for (int j2 = 0; j2 < 4; ++j2)
                dst[kl][j2] = *reinterpret_cast<const bf16x8*>(
                    src + kl * 2048 + (j2 * 64 + lane) * 8);
    };

    load_chunk(0, Bbuf[0]);

    // --- stage input tile (zero-padded halo), 16B per thread-iteration ---
    for (int i = tid; i < TR * TC * CG; i += 192) {
        int cg = i % CG;
        int pix = i / CG;
        int r = pix / TC, c = pix - r * TC;
        int gx = x0 - PAD + r, gy = y0 - PAD + c;
        uint4 v = make_uint4(0u, 0u, 0u, 0u);
        if ((unsigned)gx < (unsigned)MXY && (unsigned)gy < (unsigned)MXY)
            v = *reinterpret_cast<const uint4*>(inn + ((size_t)gx * MXY + gy) * CIN + cg * 8);
        *reinterpret_cast<uint4*>(&s_in[pix * CIP + cg * 8]) = v;
    }
    __syncthreads();  // the ONLY barrier before the epilogue

    // per-lane pixel coords for A fragments (4 m-tiles of 16 pixels)
    int prow[4], pcol[4];
#pragma unroll
    for (int i = 0; i < 4; ++i) {
        int p = wv * 64 + i * 16 + ml;
        prow[i] = p / 24;
        pcol[i] = p - prow[i] * 24;
    }

    floatx4 acc[4][4] = {};

#pragma unroll
    for (int c = 0; c < NC; ++c) {
        // prefetch next weight chunk into the other register buffer;
        // 32 MFMAs below + cross-wave overlap (3 waves/SIMD) cover L2 latency
        if (c + 1 < NC) load_chunk(c + 1, Bbuf[(c + 1) & 1]);

#pragma unroll
        for (int kl = 0; kl < CHUNK; ++kl) {
            const int kk = c * CHUNK + kl;

            int tap, chb;
            if (CIN == 16) {  // conv1: kstep spans taps 2kk, 2kk+1 (tap>=25 weights are 0)
                tap = kk * 2 + (q >> 1);
                if (tap > 24) tap = 24;
                chb = (q & 1) * 8;
            } else {          // conv2/3: kstep = half of one tap's 64 channels
                tap = kk >> 1;
                chb = (kk & 1) * 32 + q * 8;
            }
            const int dx = tap / K, dy = tap - dx * K;

            bf16x8 A[4];
#pragma unroll
            for (int i = 0; i < 4; ++i)
                A[i] = *reinterpret_cast<const bf16x8*>(
                    &s_in[((prow[i] + dx) * TC + (pcol[i] + dy)) * CIP + chb]);

#pragma unroll
            for (int i = 0; i < 4; ++i)
#pragma unroll
                for (int j2 = 0; j2 < 4; ++j2)
                    acc[i][j2] = __builtin_amdgcn_mfma_f32_16x16x32_bf16(
                        A[i], Bbuf[c & 1][kl][j2], acc[i][j2], 0, 0, 0);
        }
    }

    // --- epilogue: bias + relu, bf16 NHWC stores ---
    float b4[4];
#pragma unroll
    for (int j2 = 0; j2 < 4; ++j2) b4[j2] = bias[j2 * 16 + ml];

    short* outn = out + (size_t)n * (MXY * MXY) * 64;
#pragma unroll
    for (int i = 0; i < 4; ++i) {
#pragma unroll
        for (int r = 0; r < 4; ++r) {
            int p = wv * 64 + i * 16 + q * 4 + r;
            int row = p / 24, col = p - row * 24;
            size_t base = ((size_t)(x0 + row) * MXY + (y0 + col)) * 64;
#pragma unroll
            for (int j2 = 0; j2 < 4; ++j2) {
                float v = acc[i][j2][r] + b4[j2];
                outn[base + j2 * 16 + ml] = f2b(fmaxf(v, 0.f));
            }
        }
    }
}

// ---------------------------------------------------------------------------
// Masked gather + mean over room footprint: feat[n][r][c] (fp32 out)
// One wave per (room, sample); lane = channel (coalesced bf16 NHWC reads).
// ---------------------------------------------------------------------------
__global__ void gather_mean(const short* __restrict__ Y, const float* __restrict__ rt,
                            const int* __restrict__ pos, float* __restrict__ feat, int n0)
{
    const int r = blockIdx.x;
    const int nl = blockIdx.y;
    const int n = n0 + nl;
    const int c = threadIdx.x;  // 64
    const int px = pos[(n * RR + r) * 2 + 0];
    const int py = pos[(n * RR + r) * 2 + 1];
    const short* y = Y + (size_t)nl * (MXY * MXY) * 64;
    const float* m = rt + r * 9 * 48;   // channel 0 = room_map

    float s = 0.f, ms = 0.f;
    for (int w = 0; w < WW; ++w)
        for (int h = 0; h < HH; ++h) {
            float mv = m[w * HH + h];
            ms += mv;
            if (mv != 0.f)
                s += mv * b2f(y[((size_t)(px + w) * MXY + (py + h)) * 64 + c]);
        }
    feat[((size_t)n * RR + r) * 64 + c] = s / ms;
}

// ---------------------------------------------------------------------------
// Per-sample head: room MLP (64->128->128), room-sum, fc1 (128->256), fc2
// ---------------------------------------------------------------------------
__global__ __launch_bounds__(256) void mlp_head(const float* __restrict__ feat,
                                                const float* __restrict__ HEAD,
                                                const float* __restrict__ b1,
                                                const float* __restrict__ b2,
                                                const float* __restrict__ bf1,
                                                const float* __restrict__ bf2,
                                                float* __restrict__ outp)
{
    __shared__ __align__(16) float s_feat[RR * 64];
    __shared__ __align__(16) float s_h1[RR * 128];
    __shared__ __align__(16) float s_s[2 * 128];
    __shared__ __align__(16) float s_sf[128];
    __shared__ __align__(16) float s_t1[256];

    const int n = blockIdx.x;
    const int tid = threadIdx.x;
    const float* W1t = HEAD + F_WR1T;
    const float* W2t = HEAD + F_WR2T;
    const float* F1t = HEAD + F_F1T;
    const float* F2t = HEAD + F_F2T;

    for (int i = tid; i < RR * 64; i += 256) s_feat[i] = feat[(size_t)n * RR * 64 + i];
    __syncthreads();

    const int o = tid & 127;
    const int rh = tid >> 7;

    float acc[16];
#pragma unroll
    for (int r = 0; r < 16; ++r) acc[r] = b1[o];
    for (int c4 = 0; c4 < 16; ++c4) {
        float w0 = W1t[(c4 * 4 + 0) * 128 + o];
        float w1 = W1t[(c4 * 4 + 1) * 128 + o];
        float w2 = W1t[(c4 * 4 + 2) * 128 + o];
        float w3 = W1t[(c4 * 4 + 3) * 128 + o];
#pragma unroll
        for (int r = 0; r < 16; ++r) {
            float4 f = *reinterpret_cast<const float4*>(&s_feat[(rh * 16 + r) * 64 + c4 * 4]);
            acc[r] += f.x * w0 + f.y * w1 + f.z * w2 + f.w * w3;
        }
    }
#pragma unroll
    for (int r = 0; r < 16; ++r) s_h1[(rh * 16 + r) * 128 + o] = fmaxf(acc[r], 0.f);
    __syncthreads();

#pragma unroll
    for (int r = 0; r < 16; ++r) acc[r] = b2[o];
    for (int c4 = 0; c4 < 32; ++c4) {
        float w0 = W2t[(c4 * 4 + 0) * 128 + o];
        float w1 = W2t[(c4 * 4 + 1) * 128 + o];
        float w2 = W2t[(c4 * 4 + 2) * 128 + o];
        float w3 = W2t[(c4 * 4 + 3) * 128 + o];
#pragma unroll
        for (int r = 0; r < 16; ++r) {
            float4 f = *reinterpret_cast<const float4*>(&s_h1[(rh * 16 + r) * 128 + c4 * 4]);
            acc[r] += f.x * w0 + f.y * w1 + f.z * w2 + f.w * w3;
        }
    }
    float ps = 0.f;
#pragma unroll
    for (int r = 0; r < 16; ++r) ps += fmaxf(acc[r], 0.f);
    s_s[rh * 128 + o] = ps;
    __syncthreads();
    if (tid < 128) s_sf[tid] = s_s[tid] + s_s[128 + tid];
    __syncthreads();

    {
        float a = bf1[tid];
        for (int c4 = 0; c4 < 32; ++c4) {
            float4 f = *reinterpret_cast<const float4*>(&s_sf[c4 * 4]);
            a += f.x * F1t[(c4 * 4 + 0) * 256 + tid];
            a += f.y * F1t[(c4 * 4 + 1) * 256 + tid];
            a += f.z * F1t[(c4 * 4 + 2) * 256 + tid];
            a += f.w * F1t[(c4 * 4 + 3) * 256 + tid];
        }
        s_t1[tid] = fmaxf(a, 0.f);
    }
    __syncthreads();

    {
        float a = bf2[tid];
        for (int c4 = 0; c4 < 64; ++c4) {
            float4 f = *reinterpret_cast<const float4*>(&s_t1[c4 * 4]);
            a += f.x * F2t[(c4 * 4 + 0) * 256 + tid];
            a += f.y * F2t[(c4 * 4 + 1) * 256 + tid];
            a += f.z * F2t[(c4 * 4 + 2) * 256 + tid];
            a += f.w * F2t[(c4 * 4 + 3) * 256 + tid];
        }
        outp[(size_t)n * 256 + tid] = a;
    }
}

// ---------------------------------------------------------------------------
extern "C" void kernel_launch(void* const* d_in, const int* in_sizes, int n_in,
                              void* d_out, int out_size, void* d_ws, size_t ws_size,
                              hipStream_t stream)
{
    const int* pos = (const int*)d_in[0];
    const float* rt = (const float*)d_in[1];
    const float* emb = (const float*)d_in[2];
    const float* w1 = (const float*)d_in[3];
    const float* bc1 = (const float*)d_in[4];
    const float* w2 = (const float*)d_in[5];
    const float* bc2 = (const float*)d_in[6];
    const float* w3 = (const float*)d_in[7];
    const float* bc3 = (const float*)d_in[8];
    const float* wr1 = (const float*)d_in[9];
    const float* br1 = (const float*)d_in[10];
    const float* wr2 = (const float*)d_in[11];
    const float* br2 = (const float*)d_in[12];
    const float* wf1 = (const float*)d_in[13];
    const float* bf1 = (const float*)d_in[14];
    const float* wf2 = (const float*)d_in[15];
    const float* bf2 = (const float*)d_in[16];
    float* out = (float*)d_out;
    char* ws = (char*)d_ws;

    prep_weights<<<880, 256, 0, stream>>>(w1, w2, w3, wr1, wr2, wf1, wf2, ws);

    // pick largest batch chunk that fits the workspace
    int nc = 16;
    const int cands[4] = {256, 128, 64, 32};
    for (int k = 0; k < 4; ++k) {
        size_t need = B_CHUNK + (size_t)cands[k] * PERN_BYTES;
        if (need <= ws_size) { nc = cands[k]; break; }
    }

    short* W1F = (short*)(ws + B_W1F);
    short* W2F = (short*)(ws + B_W2F);
    short* W3F = (short*)(ws + B_W3F);
    float* HEAD = (float*)(ws + B_HEAD);
    float* FEAT = (float*)(ws + B_FEAT);
    short* Xc = (short*)(ws + B_CHUNK);
    short* YA = Xc + (size_t)nc * (MXY * MXY) * CIN1;
    short* YB = YA + (size_t)nc * (MXY * MXY) * 64;

    for (int n0 = 0; n0 < NB; n0 += nc) {
        build_x<<<nc, 256, 0, stream>>>(pos, rt, emb, Xc, n0);
        conv_mfma<16, 5, 14, 2, 24><<<dim3(27, nc), 192, 0, stream>>>(Xc, W1F, bc1, YA);
        conv_mfma<64, 3, 18, 2, 72><<<dim3(27, nc), 192, 0, stream>>>(YA, W2F, bc2, YB);
        conv_mfma<64, 3, 18, 2, 72><<<dim3(27, nc), 192, 0, stream>>>(YB, W3F, bc3, YA);
        gather_mean<<<dim3(RR, nc), 64, 0, stream>>>(YA, rt, pos, FEAT, n0);
    }

    mlp_head<<<NB, 256, 0, stream>>>(FEAT, HEAD, br1, br2, bf1, bf2, out);
}

// Round 7
// 576.419 us; speedup vs baseline: 1.2375x; 1.0583x over previous
//
#include <hip/hip_runtime.h>
#include <hip/hip_bf16.h>
#include <cstddef>

// Problem constants
#define NB 256   // batch
#define RR 32    // rooms
#define WW 8     // room width
#define HH 6     // room height
#define MXY 72   // map extent
#define EMB 6
#define CIN1 16  // 9 + 1 + 6

typedef __bf16 bf16x8 __attribute__((ext_vector_type(8)));
typedef float floatx4 __attribute__((ext_vector_type(4)));

// --- Workspace layout (byte offsets) ---------------------------------------
// conv weight fragments (bf16/short), packed in exact B-frag order
static const size_t B_W1F  = 0;         // 14 ksteps * 4096 B = 57344 (taps>=25 zero)
static const size_t B_W2F  = 57344;     // 18 * 4096 = 73728
static const size_t B_W3F  = 131072;    // 73728 -> ends 204800
static const size_t B_HEAD = 204800;    // fp32 head weights, 122880 floats = 491520 B
//   float offsets inside HEAD:
static const size_t F_WR1T = 0;         // (64,128)    8192
static const size_t F_WR2T = 8192;      // (128,128)  16384
static const size_t F_F1T  = 24576;     // (128,256)  32768
static const size_t F_F2T  = 57344;     // (256,256)  65536 -> 122880 floats
static const size_t B_FEAT = 696320;    // (256,32,64) f32 = 2097152 B
static const size_t B_CHUNK = 2793472;  // per-chunk activation buffers
// per-image bytes: X bf16 5184*16*2=165888 ; Y bf16 5184*64*2=663552 (x2)
static const size_t PERN_BYTES = 165888 + 2 * 663552;  // 1492992

__device__ inline short f2b(float f) {
    unsigned u = __builtin_bit_cast(unsigned, f);
    unsigned r = (u + 0x7fffu + ((u >> 16) & 1u)) >> 16;
    return (short)r;
}
__device__ inline float b2f(short s) {
    unsigned u = ((unsigned)(unsigned short)s) << 16;
    return __builtin_bit_cast(float, u);
}

// ---------------------------------------------------------------------------
// Prep: conv weights fp32 -> bf16 B-fragment order; head weights transposed.
// Fragment order: [kk][ntile][lane][j] ; virtual k = kk*32 + (lane>>4)*8 + j
// oc = ntile*16 + (lane&15) ; (tap, ci) = (k / CIN, k % CIN)
// ---------------------------------------------------------------------------
__global__ void prep_weights(const float* __restrict__ w1, const float* __restrict__ w2,
                             const float* __restrict__ w3, const float* __restrict__ wr1,
                             const float* __restrict__ wr2, const float* __restrict__ wf1,
                             const float* __restrict__ wf2, char* __restrict__ ws)
{
    short* W1F = (short*)(ws + B_W1F);
    short* W2F = (short*)(ws + B_W2F);
    short* W3F = (short*)(ws + B_W3F);
    float* HEAD = (float*)(ws + B_HEAD);

    int idx = blockIdx.x * 256 + threadIdx.x;
    if (idx < 28672) {  // conv1: 14 ksteps (padded), CIN=16, taps 0..24 real
        int j = idx & 7, lane = (idx >> 3) & 63, nt = (idx >> 9) & 3, kk = idx >> 11;
        int k = kk * 32 + (lane >> 4) * 8 + j;
        int oc = nt * 16 + (lane & 15);
        int tap = k >> 4, ci = k & 15;
        float v = (tap < 25) ? w1[(oc * 16 + ci) * 25 + tap] : 0.f;
        W1F[idx] = f2b(v);
        return;
    }
    idx -= 28672;
    if (idx < 36864) {  // conv2: 18 ksteps, CIN=64, 9 taps
        int j = idx & 7, lane = (idx >> 3) & 63, nt = (idx >> 9) & 3, kk = idx >> 11;
        int k = kk * 32 + (lane >> 4) * 8 + j;
        int oc = nt * 16 + (lane & 15);
        int tap = k >> 6, ci = k & 63;
        W2F[idx] = f2b(w2[(oc * 64 + ci) * 9 + tap]);
        return;
    }
    idx -= 36864;
    if (idx < 36864) {  // conv3
        int j = idx & 7, lane = (idx >> 3) & 63, nt = (idx >> 9) & 3, kk = idx >> 11;
        int k = kk * 32 + (lane >> 4) * 8 + j;
        int oc = nt * 16 + (lane & 15);
        int tap = k >> 6, ci = k & 63;
        W3F[idx] = f2b(w3[(oc * 64 + ci) * 9 + tap]);
        return;
    }
    idx -= 36864;
    if (idx < 8192)  { int o = idx & 127, c = idx >> 7; HEAD[F_WR1T + idx] = wr1[o * 64 + c]; return; }
    idx -= 8192;
    if (idx < 16384) { int o = idx & 127, c = idx >> 7; HEAD[F_WR2T + idx] = wr2[o * 128 + c]; return; }
    idx -= 16384;
    if (idx < 32768) { int o = idx & 255, c = idx >> 8; HEAD[F_F1T + idx] = wf1[o * 128 + c]; return; }
    idx -= 32768;
    if (idx < 65536) { int o = idx & 255, c = idx >> 8; HEAD[F_F2T + idx] = wf2[o * 256 + c]; return; }
}

// ---------------------------------------------------------------------------
// Build X (nc, 72, 72, 16) NHWC bf16: scatter room tensors + embedding, ch9=1
// One block per sample; rooms serialized via syncthreads (no atomics).
// ---------------------------------------------------------------------------
__global__ __launch_bounds__(256) void build_x(const int* __restrict__ pos,
                                               const float* __restrict__ rt,
                                               const float* __restrict__ emb,
                                               short* __restrict__ X, int n0)
{
    const int nl = blockIdx.x;
    const int n = n0 + nl;
    const int tid = threadIdx.x;
    short* Xn = X + (size_t)nl * (MXY * MXY) * CIN1;

    const short ONE = 0x3F80;  // bf16 1.0
    for (int i = tid; i < MXY * MXY * CIN1; i += 256)
        Xn[i] = ((i & 15) == 9) ? ONE : (short)0;
    __syncthreads();

    for (int r = 0; r < RR; ++r) {
        int px = pos[(n * RR + r) * 2 + 0];
        int py = pos[(n * RR + r) * 2 + 1];
        for (int i = tid; i < 15 * WW * HH; i += 256) {
            int c15 = i / 48;
            int j = i - c15 * 48;       // w*6 + h
            int w = j / 6, h = j - w * 6;
            float v; int c;
            if (c15 < 9) { v = rt[(r * 9 + c15) * 48 + j]; c = c15; }
            else { v = emb[r * EMB + (c15 - 9)] * rt[(r * 9 + 0) * 48 + j]; c = c15 + 1; }
            size_t a = ((size_t)(px + w) * MXY + (py + h)) * CIN1 + c;
            Xn[a] = f2b(b2f(Xn[a]) + v);
        }
        __syncthreads();
    }
}

// ---------------------------------------------------------------------------
// MFMA conv + bias + ReLU, NHWC bf16. Block = 4 waves (256 thr),
// tile 8x24 px x 64 oc. Wave tile: 96 px (6 m-tiles) x 32 oc (2 n-tiles)
//   wave wv: px-group = wv>>1 (0,1: 96 px each), oc-group = wv&1 (0,1).
// RESHAPED from 4m x 4n (rounds 2-6): acc 64->48, Bbuf 64->32, A 16->24
//   -> natural footprint ~110-125 unified regs -> 4 waves/SIMD, and
//   LDS 37.4 KB -> 4 blocks/CU -> ~16 waves/CU (round 6 was stuck at 2
//   waves/SIMD: 128 VGPR + 64 AGPR = 192 unified > 170-reg line).
// Cost: each A frag is read by 2 waves (two oc-groups) -> A-LDS traffic 2x,
//   still at/below the MFMA floor. B traffic unchanged.
// Weights stay in registers (B frags from L2, ping-pong, CHUNK=2);
// K-loop has no barriers; only wave-local vmcnt/lgkm waits.
// ---------------------------------------------------------------------------
template <int CIN, int K, int NKP, int CHUNK, int CIP>
__global__ __launch_bounds__(256, 2) void conv_mfma(const short* __restrict__ in,
                                                    const short* __restrict__ wF,
                                                    const float* __restrict__ bias,
                                                    short* __restrict__ out)
{
    constexpr int PAD = K / 2;
    constexpr int TR = 8 + K - 1;
    constexpr int TC = 24 + K - 1;
    constexpr int CG = CIN / 8;
    constexpr int NC = NKP / CHUNK;            // number of K chunks

    __shared__ __align__(16) short s_in[TR * TC * CIP];

    const int tid = threadIdx.x;
    const int lane = tid & 63;
    const int wv = tid >> 6;
    const int pxg = wv >> 1;       // px-group: 0 or 1 (96 px each)
    const int og = wv & 1;         // oc-group: 0 or 1 (32 oc each)
    const int ml = lane & 15;
    const int q = lane >> 4;
    const int n = blockIdx.y;
    const int x0 = (blockIdx.x / 3) * 8;
    const int y0 = (blockIdx.x % 3) * 24;

    const short* inn = in + (size_t)n * (MXY * MXY) * CIN;

    // B-fragment register ping-pong: [buf][kstep-in-chunk][local n-tile]
    bf16x8 Bbuf[2][CHUNK][2];
    auto load_chunk = [&](int c, bf16x8 (*dst)[2]) {
        const short* src = wF + (size_t)c * CHUNK * 2048;
#pragma unroll
        for (int kl = 0; kl < CHUNK; ++kl)
#pragma unroll
            for (int j2 = 0; j2 < 2; ++j2)
                dst[kl][j2] = *reinterpret_cast<const bf16x8*>(
                    src + kl * 2048 + (((og * 2 + j2) * 64 + lane)) * 8);
    };

    load_chunk(0, Bbuf[0]);

    // --- stage input tile (zero-padded halo), 16B per thread-iteration ---
    for (int i = tid; i < TR * TC * CG; i += 256) {
        int cg = i % CG;
        int pix = i / CG;
        int r = pix / TC, c = pix - r * TC;
        int gx = x0 - PAD + r, gy = y0 - PAD + c;
        uint4 v = make_uint4(0u, 0u, 0u, 0u);
        if ((unsigned)gx < (unsigned)MXY && (unsigned)gy < (unsigned)MXY)
            v = *reinterpret_cast<const uint4*>(inn + ((size_t)gx * MXY + gy) * CIN + cg * 8);
        *reinterpret_cast<uint4*>(&s_in[pix * CIP + cg * 8]) = v;
    }
    __syncthreads();  // the ONLY barrier before the epilogue

    // per-lane pixel coords for A fragments (6 m-tiles of 16 pixels)
    int prow[6], pcol[6];
#pragma unroll
    for (int i = 0; i < 6; ++i) {
        int p = pxg * 96 + i * 16 + ml;
        prow[i] = p / 24;
        pcol[i] = p - prow[i] * 24;
    }

    floatx4 acc[6][2] = {};

#pragma unroll
    for (int c = 0; c < NC; ++c) {
        // prefetch next weight chunk into the other register buffer;
        // 24 MFMAs below + 4 waves/SIMD cross-wave overlap cover L2 latency
        if (c + 1 < NC) load_chunk(c + 1, Bbuf[(c + 1) & 1]);

#pragma unroll
        for (int kl = 0; kl < CHUNK; ++kl) {
            const int kk = c * CHUNK + kl;

            int tap, chb;
            if (CIN == 16) {  // conv1: kstep spans taps 2kk, 2kk+1 (tap>=25 weights are 0)
                tap = kk * 2 + (q >> 1);
                if (tap > 24) tap = 24;
                chb = (q & 1) * 8;
            } else {          // conv2/3: kstep = half of one tap's 64 channels
                tap = kk >> 1;
                chb = (kk & 1) * 32 + q * 8;
            }
            const int dx = tap / K, dy = tap - dx * K;

#pragma unroll
            for (int i = 0; i < 6; ++i) {
                bf16x8 A = *reinterpret_cast<const bf16x8*>(
                    &s_in[((prow[i] + dx) * TC + (pcol[i] + dy)) * CIP + chb]);
#pragma unroll
                for (int j2 = 0; j2 < 2; ++j2)
                    acc[i][j2] = __builtin_amdgcn_mfma_f32_16x16x32_bf16(
                        A, Bbuf[c & 1][kl][j2], acc[i][j2], 0, 0, 0);
            }
        }
    }

    // --- epilogue: bias + relu, bf16 NHWC stores ---
    float b2[2];
#pragma unroll
    for (int j2 = 0; j2 < 2; ++j2) b2[j2] = bias[(og * 2 + j2) * 16 + ml];

    short* outn = out + (size_t)n * (MXY * MXY) * 64;
#pragma unroll
    for (int i = 0; i < 6; ++i) {
#pragma unroll
        for (int r = 0; r < 4; ++r) {
            int p = pxg * 96 + i * 16 + q * 4 + r;
            int row = p / 24, col = p - row * 24;
            size_t base = ((size_t)(x0 + row) * MXY + (y0 + col)) * 64;
#pragma unroll
            for (int j2 = 0; j2 < 2; ++j2) {
                float v = acc[i][j2][r] + b2[j2];
                outn[base + (og * 2 + j2) * 16 + ml] = f2b(fmaxf(v, 0.f));
            }
        }
    }
}

// ---------------------------------------------------------------------------
// Masked gather + mean over room footprint: feat[n][r][c] (fp32 out)
// One wave per (room, sample); lane = channel (coalesced bf16 NHWC reads).
// ---------------------------------------------------------------------------
__global__ void gather_mean(const short* __restrict__ Y, const float* __restrict__ rt,
                            const int* __restrict__ pos, float* __restrict__ feat, int n0)
{
    const int r = blockIdx.x;
    const int nl = blockIdx.y;
    const int n = n0 + nl;
    const int c = threadIdx.x;  // 64
    const int px = pos[(n * RR + r) * 2 + 0];
    const int py = pos[(n * RR + r) * 2 + 1];
    const short* y = Y + (size_t)nl * (MXY * MXY) * 64;
    const float* m = rt + r * 9 * 48;   // channel 0 = room_map

    float s = 0.f, ms = 0.f;
    for (int w = 0; w < WW; ++w)
        for (int h = 0; h < HH; ++h) {
            float mv = m[w * HH + h];
            ms += mv;
            if (mv != 0.f)
                s += mv * b2f(y[((size_t)(px + w) * MXY + (py + h)) * 64 + c]);
        }
    feat[((size_t)n * RR + r) * 64 + c] = s / ms;
}

// ---------------------------------------------------------------------------
// Per-sample head: room MLP (64->128->128), room-sum, fc1 (128->256), fc2
// ---------------------------------------------------------------------------
__global__ __launch_bounds__(256) void mlp_head(const float* __restrict__ feat,
                                                const float* __restrict__ HEAD,
                                                const float* __restrict__ b1,
                                                const float* __restrict__ b2,
                                                const float* __restrict__ bf1,
                                                const float* __restrict__ bf2,
                                                float* __restrict__ outp)
{
    __shared__ __align__(16) float s_feat[RR * 64];
    __shared__ __align__(16) float s_h1[RR * 128];
    __shared__ __align__(16) float s_s[2 * 128];
    __shared__ __align__(16) float s_sf[128];
    __shared__ __align__(16) float s_t1[256];

    const int n = blockIdx.x;
    const int tid = threadIdx.x;
    const float* W1t = HEAD + F_WR1T;
    const float* W2t = HEAD + F_WR2T;
    const float* F1t = HEAD + F_F1T;
    const float* F2t = HEAD + F_F2T;

    for (int i = tid; i < RR * 64; i += 256) s_feat[i] = feat[(size_t)n * RR * 64 + i];
    __syncthreads();

    const int o = tid & 127;
    const int rh = tid >> 7;

    float acc[16];
#pragma unroll
    for (int r = 0; r < 16; ++r) acc[r] = b1[o];
    for (int c4 = 0; c4 < 16; ++c4) {
        float w0 = W1t[(c4 * 4 + 0) * 128 + o];
        float w1 = W1t[(c4 * 4 + 1) * 128 + o];
        float w2 = W1t[(c4 * 4 + 2) * 128 + o];
        float w3 = W1t[(c4 * 4 + 3) * 128 + o];
#pragma unroll
        for (int r = 0; r < 16; ++r) {
            float4 f = *reinterpret_cast<const float4*>(&s_feat[(rh * 16 + r) * 64 + c4 * 4]);
            acc[r] += f.x * w0 + f.y * w1 + f.z * w2 + f.w * w3;
        }
    }
#pragma unroll
    for (int r = 0; r < 16; ++r) s_h1[(rh * 16 + r) * 128 + o] = fmaxf(acc[r], 0.f);
    __syncthreads();

#pragma unroll
    for (int r = 0; r < 16; ++r) acc[r] = b2[o];
    for (int c4 = 0; c4 < 32; ++c4) {
        float w0 = W2t[(c4 * 4 + 0) * 128 + o];
        float w1 = W2t[(c4 * 4 + 1) * 128 + o];
        float w2 = W2t[(c4 * 4 + 2) * 128 + o];
        float w3 = W2t[(c4 * 4 + 3) * 128 + o];
#pragma unroll
        for (int r = 0; r < 16; ++r) {
            float4 f = *reinterpret_cast<const float4*>(&s_h1[(rh * 16 + r) * 128 + c4 * 4]);
            acc[r] += f.x * w0 + f.y * w1 + f.z * w2 + f.w * w3;
        }
    }
    float ps = 0.f;
#pragma unroll
    for (int r = 0; r < 16; ++r) ps += fmaxf(acc[r], 0.f);
    s_s[rh * 128 + o] = ps;
    __syncthreads();
    if (tid < 128) s_sf[tid] = s_s[tid] + s_s[128 + tid];
    __syncthreads();

    {
        float a = bf1[tid];
        for (int c4 = 0; c4 < 32; ++c4) {
            float4 f = *reinterpret_cast<const float4*>(&s_sf[c4 * 4]);
            a += f.x * F1t[(c4 * 4 + 0) * 256 + tid];
            a += f.y * F1t[(c4 * 4 + 1) * 256 + tid];
            a += f.z * F1t[(c4 * 4 + 2) * 256 + tid];
            a += f.w * F1t[(c4 * 4 + 3) * 256 + tid];
        }
        s_t1[tid] = fmaxf(a, 0.f);
    }
    __syncthreads();

    {
        float a = bf2[tid];
        for (int c4 = 0; c4 < 64; ++c4) {
            float4 f = *reinterpret_cast<const float4*>(&s_t1[c4 * 4]);
            a += f.x * F2t[(c4 * 4 + 0) * 256 + tid];
            a += f.y * F2t[(c4 * 4 + 1) * 256 + tid];
            a += f.z * F2t[(c4 * 4 + 2) * 256 + tid];
            a += f.w * F2t[(c4 * 4 + 3) * 256 + tid];
        }
        outp[(size_t)n * 256 + tid] = a;
    }
}

// ---------------------------------------------------------------------------
extern "C" void kernel_launch(void* const* d_in, const int* in_sizes, int n_in,
                              void* d_out, int out_size, void* d_ws, size_t ws_size,
                              hipStream_t stream)
{
    const int* pos = (const int*)d_in[0];
    const float* rt = (const float*)d_in[1];
    const float* emb = (const float*)d_in[2];
    const float* w1 = (const float*)d_in[3];
    const float* bc1 = (const float*)d_in[4];
    const float* w2 = (const float*)d_in[5];
    const float* bc2 = (const float*)d_in[6];
    const float* w3 = (const float*)d_in[7];
    const float* bc3 = (const float*)d_in[8];
    const float* wr1 = (const float*)d_in[9];
    const float* br1 = (const float*)d_in[10];
    const float* wr2 = (const float*)d_in[11];
    const float* br2 = (const float*)d_in[12];
    const float* wf1 = (const float*)d_in[13];
    const float* bf1 = (const float*)d_in[14];
    const float* wf2 = (const float*)d_in[15];
    const float* bf2 = (const float*)d_in[16];
    float* out = (float*)d_out;
    char* ws = (char*)d_ws;

    prep_weights<<<880, 256, 0, stream>>>(w1, w2, w3, wr1, wr2, wf1, wf2, ws);

    // pick largest batch chunk that fits the workspace
    int nc = 16;
    const int cands[4] = {256, 128, 64, 32};
    for (int k = 0; k < 4; ++k) {
        size_t need = B_CHUNK + (size_t)cands[k] * PERN_BYTES;
        if (need <= ws_size) { nc = cands[k]; break; }
    }

    short* W1F = (short*)(ws + B_W1F);
    short* W2F = (short*)(ws + B_W2F);
    short* W3F = (short*)(ws + B_W3F);
    float* HEAD = (float*)(ws + B_HEAD);
    float* FEAT = (float*)(ws + B_FEAT);
    short* Xc = (short*)(ws + B_CHUNK);
    short* YA = Xc + (size_t)nc * (MXY * MXY) * CIN1;
    short* YB = YA + (size_t)nc * (MXY * MXY) * 64;

    for (int n0 = 0; n0 < NB; n0 += nc) {
        build_x<<<nc, 256, 0, stream>>>(pos, rt, emb, Xc, n0);
        conv_mfma<16, 5, 14, 2, 24><<<dim3(27, nc), 256, 0, stream>>>(Xc, W1F, bc1, YA);
        conv_mfma<64, 3, 18, 2, 72><<<dim3(27, nc), 256, 0, stream>>>(YA, W2F, bc2, YB);
        conv_mfma<64, 3, 18, 2, 72><<<dim3(27, nc), 256, 0, stream>>>(YB, W3F, bc3, YA);
        gather_mean<<<dim3(RR, nc), 64, 0, stream>>>(YA, rt, pos, FEAT, n0);
    }

    mlp_head<<<NB, 256, 0, stream>>>(FEAT, HEAD, br1, br2, bf1, bf2, out);
}

// Round 8
// 475.252 us; speedup vs baseline: 1.5009x; 1.2129x over previous
//
#include <hip/hip_runtime.h>
#include <hip/hip_bf16.h>
#include <cstddef>

// Problem constants
#define NB 256   // batch
#define RR 32    // rooms
#define WW 8     // room width
#define HH 6     // room height
#define MXY 72   // map extent
#define EMB 6
#define CIN1 16  // 9 + 1 + 6

typedef __bf16 bf16x8 __attribute__((ext_vector_type(8)));
typedef float floatx4 __attribute__((ext_vector_type(4)));

// --- Workspace layout (byte offsets) ---------------------------------------
// conv weight fragments (bf16/short), packed in exact B-frag order
static const size_t B_W1F  = 0;         // 14 ksteps * 4096 B = 57344 (taps>=25 zero)
static const size_t B_W2F  = 57344;     // 18 * 4096 = 73728
static const size_t B_W3F  = 131072;    // 73728 -> ends 204800
static const size_t B_HEAD = 204800;    // fp32 head weights, 122880 floats = 491520 B
//   float offsets inside HEAD:
static const size_t F_WR1T = 0;         // (64,128)    8192
static const size_t F_WR2T = 8192;      // (128,128)  16384
static const size_t F_F1T  = 24576;     // (128,256)  32768
static const size_t F_F2T  = 57344;     // (256,256)  65536 -> 122880 floats
static const size_t B_FEAT = 696320;    // (256,32,64) f32 = 2097152 B
static const size_t B_CHUNK = 2793472;  // per-chunk activation buffers
// per-image bytes: X bf16 5184*16*2=165888 ; Y bf16 5184*64*2=663552 (x2)
static const size_t PERN_BYTES = 165888 + 2 * 663552;  // 1492992

__device__ inline short f2b(float f) {
    unsigned u = __builtin_bit_cast(unsigned, f);
    unsigned r = (u + 0x7fffu + ((u >> 16) & 1u)) >> 16;
    return (short)r;
}
__device__ inline float b2f(short s) {
    unsigned u = ((unsigned)(unsigned short)s) << 16;
    return __builtin_bit_cast(float, u);
}

// ---------------------------------------------------------------------------
// Prep: conv weights fp32 -> bf16 B-fragment order; head weights transposed.
// Fragment order: [kk][ntile][lane][j] ; virtual k = kk*32 + (lane>>4)*8 + j
// oc = ntile*16 + (lane&15) ; (tap, ci) = (k / CIN, k % CIN)
// ---------------------------------------------------------------------------
__global__ void prep_weights(const float* __restrict__ w1, const float* __restrict__ w2,
                             const float* __restrict__ w3, const float* __restrict__ wr1,
                             const float* __restrict__ wr2, const float* __restrict__ wf1,
                             const float* __restrict__ wf2, char* __restrict__ ws)
{
    short* W1F = (short*)(ws + B_W1F);
    short* W2F = (short*)(ws + B_W2F);
    short* W3F = (short*)(ws + B_W3F);
    float* HEAD = (float*)(ws + B_HEAD);

    int idx = blockIdx.x * 256 + threadIdx.x;
    if (idx < 28672) {  // conv1: 14 ksteps (padded), CIN=16, taps 0..24 real
        int j = idx & 7, lane = (idx >> 3) & 63, nt = (idx >> 9) & 3, kk = idx >> 11;
        int k = kk * 32 + (lane >> 4) * 8 + j;
        int oc = nt * 16 + (lane & 15);
        int tap = k >> 4, ci = k & 15;
        float v = (tap < 25) ? w1[(oc * 16 + ci) * 25 + tap] : 0.f;
        W1F[idx] = f2b(v);
        return;
    }
    idx -= 28672;
    if (idx < 36864) {  // conv2: 18 ksteps, CIN=64, 9 taps
        int j = idx & 7, lane = (idx >> 3) & 63, nt = (idx >> 9) & 3, kk = idx >> 11;
        int k = kk * 32 + (lane >> 4) * 8 + j;
        int oc = nt * 16 + (lane & 15);
        int tap = k >> 6, ci = k & 63;
        W2F[idx] = f2b(w2[(oc * 64 + ci) * 9 + tap]);
        return;
    }
    idx -= 36864;
    if (idx < 36864) {  // conv3
        int j = idx & 7, lane = (idx >> 3) & 63, nt = (idx >> 9) & 3, kk = idx >> 11;
        int k = kk * 32 + (lane >> 4) * 8 + j;
        int oc = nt * 16 + (lane & 15);
        int tap = k >> 6, ci = k & 63;
        W3F[idx] = f2b(w3[(oc * 64 + ci) * 9 + tap]);
        return;
    }
    idx -= 36864;
    if (idx < 8192)  { int o = idx & 127, c = idx >> 7; HEAD[F_WR1T + idx] = wr1[o * 64 + c]; return; }
    idx -= 8192;
    if (idx < 16384) { int o = idx & 127, c = idx >> 7; HEAD[F_WR2T + idx] = wr2[o * 128 + c]; return; }
    idx -= 16384;
    if (idx < 32768) { int o = idx & 255, c = idx >> 8; HEAD[F_F1T + idx] = wf1[o * 128 + c]; return; }
    idx -= 32768;
    if (idx < 65536) { int o = idx & 255, c = idx >> 8; HEAD[F_F2T + idx] = wf2[o * 256 + c]; return; }
}

// ---------------------------------------------------------------------------
// Build X (nc, 72, 72, 16) NHWC bf16 — GATHER style (round 8 rewrite):
// thread = one output pixel; loop over 32 rooms with a bounds test and
// accumulate in fp32 registers (single bf16 round at the end). Replaces the
// 32x-serialized-barrier scatter kernel (only nc blocks, room loop serial).
// ---------------------------------------------------------------------------
__global__ __launch_bounds__(256) void build_x(const int* __restrict__ pos,
                                               const float* __restrict__ rt,
                                               const float* __restrict__ emb,
                                               short* __restrict__ X, int n0)
{
    const int nl = blockIdx.y;
    const int n = n0 + nl;
    const int p = blockIdx.x * 256 + threadIdx.x;

    __shared__ int s_px[RR], s_py[RR];
    __shared__ float s_emb[RR * EMB];
    if (threadIdx.x < RR) {
        s_px[threadIdx.x] = pos[(n * RR + threadIdx.x) * 2 + 0];
        s_py[threadIdx.x] = pos[(n * RR + threadIdx.x) * 2 + 1];
    }
    for (int i = threadIdx.x; i < RR * EMB; i += 256) s_emb[i] = emb[i];
    __syncthreads();
    if (p >= MXY * MXY) return;

    const int gx = p / MXY, gy = p - (p / MXY) * MXY;

    float acc[16];
#pragma unroll
    for (int c = 0; c < 16; ++c) acc[c] = 0.f;
    acc[9] = 1.f;

    for (int r = 0; r < RR; ++r) {
        int w = gx - s_px[r], h = gy - s_py[r];
        if ((unsigned)w < (unsigned)WW && (unsigned)h < (unsigned)HH) {
            int j = w * HH + h;
            const float* rr = rt + r * 9 * 48;
#pragma unroll
            for (int c = 0; c < 9; ++c) acc[c] += rr[c * 48 + j];
            float m = rr[j];  // channel 0 = room_map
#pragma unroll
            for (int e = 0; e < EMB; ++e) acc[10 + e] += s_emb[r * EMB + e] * m;
        }
    }

    short o[16];
#pragma unroll
    for (int c = 0; c < 16; ++c) o[c] = f2b(acc[c]);
    short* dst = X + ((size_t)nl * (MXY * MXY) + p) * CIN1;
    *reinterpret_cast<uint4*>(dst) = *reinterpret_cast<uint4*>(o);
    *reinterpret_cast<uint4*>(dst + 8) = *reinterpret_cast<uint4*>(o + 8);
}

// ---------------------------------------------------------------------------
// MFMA conv + bias + ReLU, NHWC bf16. Block = 4 waves (256 thr),
// tile 8x24 px x 64 oc. Wave tile: 48 px (3 m-tiles) x 64 oc (4 n-tiles).
// Design (round 8): MFMA:A-read ratio = ntiles = 4 >= 2.7 (LDS/MFMA pipe
// balance) AND unique A-reads (waves split pixels, not oc — round 7's
// 6m x 2n doubled A-LDS traffic and became LDS-pipe-bound, conflicts 2x).
// B frags per-wave from L2 (L1-absorbed across waves; FETCH stayed flat),
// CHUNK=1 ping-pong: prefetch kstep kk+1 (4 x dwordx4) before computing kk
// (12 MFMAs ~ 230 cyc cover L2 latency).
// Reg budget: 48 acc + 32 B + 12 A + ~15 misc ~= 107 -> bounds(256,3)
// (budget 170, slack ~60 — safe, unlike round 5's slack 16 which spilled).
// ---------------------------------------------------------------------------
template <int CIN, int K, int NKP, int CIP>
__global__ __launch_bounds__(256, 3) void conv_mfma(const short* __restrict__ in,
                                                    const short* __restrict__ wF,
                                                    const float* __restrict__ bias,
                                                    short* __restrict__ out)
{
    constexpr int PAD = K / 2;
    constexpr int TR = 8 + K - 1;
    constexpr int TC = 24 + K - 1;
    constexpr int CG = CIN / 8;

    __shared__ __align__(16) short s_in[TR * TC * CIP];

    const int tid = threadIdx.x;
    const int lane = tid & 63;
    const int wv = tid >> 6;       // 0..3: px-group (48 px each)
    const int ml = lane & 15;
    const int q = lane >> 4;
    const int n = blockIdx.y;
    const int x0 = (blockIdx.x / 3) * 8;
    const int y0 = (blockIdx.x % 3) * 24;

    const short* inn = in + (size_t)n * (MXY * MXY) * CIN;

    // B-fragment register ping-pong: [buf][ntile], one kstep per buffer
    bf16x8 Bbuf[2][4];
    auto load_k = [&](int kk, bf16x8* dst) {
        const short* src = wF + (size_t)kk * 2048;
#pragma unroll
        for (int j2 = 0; j2 < 4; ++j2)
            dst[j2] = *reinterpret_cast<const bf16x8*>(src + (j2 * 64 + lane) * 8);
    };

    load_k(0, Bbuf[0]);

    // --- stage input tile (zero-padded halo), 16B per thread-iteration ---
    for (int i = tid; i < TR * TC * CG; i += 256) {
        int cg = i % CG;
        int pix = i / CG;
        int r = pix / TC, c = pix - r * TC;
        int gx = x0 - PAD + r, gy = y0 - PAD + c;
        uint4 v = make_uint4(0u, 0u, 0u, 0u);
        if ((unsigned)gx < (unsigned)MXY && (unsigned)gy < (unsigned)MXY)
            v = *reinterpret_cast<const uint4*>(inn + ((size_t)gx * MXY + gy) * CIN + cg * 8);
        *reinterpret_cast<uint4*>(&s_in[pix * CIP + cg * 8]) = v;
    }
    __syncthreads();  // the ONLY barrier before the epilogue

    // per-lane pixel coords for A fragments (3 m-tiles of 16 pixels)
    int prow[3], pcol[3];
#pragma unroll
    for (int i = 0; i < 3; ++i) {
        int p = wv * 48 + i * 16 + ml;
        prow[i] = p / 24;
        pcol[i] = p - prow[i] * 24;
    }

    floatx4 acc[3][4] = {};

#pragma unroll
    for (int kk = 0; kk < NKP; ++kk) {
        // prefetch next kstep's B frags into the other buffer (wave-local
        // vmcnt only; 12 MFMAs below cover L2 latency)
        if (kk + 1 < NKP) load_k(kk + 1, Bbuf[(kk + 1) & 1]);

        int tap, chb;
        if (CIN == 16) {  // conv1: kstep spans taps 2kk, 2kk+1 (tap>=25 weights are 0)
            tap = kk * 2 + (q >> 1);
            if (tap > 24) tap = 24;
            chb = (q & 1) * 8;
        } else {          // conv2/3: kstep = half of one tap's 64 channels
            tap = kk >> 1;
            chb = (kk & 1) * 32 + q * 8;
        }
        const int dx = tap / K, dy = tap - dx * K;

#pragma unroll
        for (int i = 0; i < 3; ++i) {
            bf16x8 A = *reinterpret_cast<const bf16x8*>(
                &s_in[((prow[i] + dx) * TC + (pcol[i] + dy)) * CIP + chb]);
#pragma unroll
            for (int j2 = 0; j2 < 4; ++j2)
                acc[i][j2] = __builtin_amdgcn_mfma_f32_16x16x32_bf16(
                    A, Bbuf[kk & 1][j2], acc[i][j2], 0, 0, 0);
        }
    }

    // --- epilogue: bias + relu, bf16 NHWC stores ---
    float b4[4];
#pragma unroll
    for (int j2 = 0; j2 < 4; ++j2) b4[j2] = bias[j2 * 16 + ml];

    short* outn = out + (size_t)n * (MXY * MXY) * 64;
#pragma unroll
    for (int i = 0; i < 3; ++i) {
#pragma unroll
        for (int r = 0; r < 4; ++r) {
            int p = wv * 48 + i * 16 + q * 4 + r;
            int row = p / 24, col = p - row * 24;
            size_t base = ((size_t)(x0 + row) * MXY + (y0 + col)) * 64;
#pragma unroll
            for (int j2 = 0; j2 < 4; ++j2) {
                float v = acc[i][j2][r] + b4[j2];
                outn[base + j2 * 16 + ml] = f2b(fmaxf(v, 0.f));
            }
        }
    }
}

// ---------------------------------------------------------------------------
// Masked gather + mean over room footprint: feat[n][r][c] (fp32 out)
// One wave per (room, sample); lane = channel (coalesced bf16 NHWC reads).
// ---------------------------------------------------------------------------
__global__ void gather_mean(const short* __restrict__ Y, const float* __restrict__ rt,
                            const int* __restrict__ pos, float* __restrict__ feat, int n0)
{
    const int r = blockIdx.x;
    const int nl = blockIdx.y;
    const int n = n0 + nl;
    const int c = threadIdx.x;  // 64
    const int px = pos[(n * RR + r) * 2 + 0];
    const int py = pos[(n * RR + r) * 2 + 1];
    const short* y = Y + (size_t)nl * (MXY * MXY) * 64;
    const float* m = rt + r * 9 * 48;   // channel 0 = room_map

    float s = 0.f, ms = 0.f;
    for (int w = 0; w < WW; ++w)
        for (int h = 0; h < HH; ++h) {
            float mv = m[w * HH + h];
            ms += mv;
            if (mv != 0.f)
                s += mv * b2f(y[((size_t)(px + w) * MXY + (py + h)) * 64 + c]);
        }
    feat[((size_t)n * RR + r) * 64 + c] = s / ms;
}

// ---------------------------------------------------------------------------
// Per-sample head: room MLP (64->128->128), room-sum, fc1 (128->256), fc2
// ---------------------------------------------------------------------------
__global__ __launch_bounds__(256) void mlp_head(const float* __restrict__ feat,
                                                const float* __restrict__ HEAD,
                                                const float* __restrict__ b1,
                                                const float* __restrict__ b2,
                                                const float* __restrict__ bf1,
                                                const float* __restrict__ bf2,
                                                float* __restrict__ outp)
{
    __shared__ __align__(16) float s_feat[RR * 64];
    __shared__ __align__(16) float s_h1[RR * 128];
    __shared__ __align__(16) float s_s[2 * 128];
    __shared__ __align__(16) float s_sf[128];
    __shared__ __align__(16) float s_t1[256];

    const int n = blockIdx.x;
    const int tid = threadIdx.x;
    const float* W1t = HEAD + F_WR1T;
    const float* W2t = HEAD + F_WR2T;
    const float* F1t = HEAD + F_F1T;
    const float* F2t = HEAD + F_F2T;

    for (int i = tid; i < RR * 64; i += 256) s_feat[i] = feat[(size_t)n * RR * 64 + i];
    __syncthreads();

    const int o = tid & 127;
    const int rh = tid >> 7;

    float acc[16];
#pragma unroll
    for (int r = 0; r < 16; ++r) acc[r] = b1[o];
    for (int c4 = 0; c4 < 16; ++c4) {
        float w0 = W1t[(c4 * 4 + 0) * 128 + o];
        float w1 = W1t[(c4 * 4 + 1) * 128 + o];
        float w2 = W1t[(c4 * 4 + 2) * 128 + o];
        float w3 = W1t[(c4 * 4 + 3) * 128 + o];
#pragma unroll
        for (int r = 0; r < 16; ++r) {
            float4 f = *reinterpret_cast<const float4*>(&s_feat[(rh * 16 + r) * 64 + c4 * 4]);
            acc[r] += f.x * w0 + f.y * w1 + f.z * w2 + f.w * w3;
        }
    }
#pragma unroll
    for (int r = 0; r < 16; ++r) s_h1[(rh * 16 + r) * 128 + o] = fmaxf(acc[r], 0.f);
    __syncthreads();

#pragma unroll
    for (int r = 0; r < 16; ++r) acc[r] = b2[o];
    for (int c4 = 0; c4 < 32; ++c4) {
        float w0 = W2t[(c4 * 4 + 0) * 128 + o];
        float w1 = W2t[(c4 * 4 + 1) * 128 + o];
        float w2 = W2t[(c4 * 4 + 2) * 128 + o];
        float w3 = W2t[(c4 * 4 + 3) * 128 + o];
#pragma unroll
        for (int r = 0; r < 16; ++r) {
            float4 f = *reinterpret_cast<const float4*>(&s_h1[(rh * 16 + r) * 128 + c4 * 4]);
            acc[r] += f.x * w0 + f.y * w1 + f.z * w2 + f.w * w3;
        }
    }
    float ps = 0.f;
#pragma unroll
    for (int r = 0; r < 16; ++r) ps += fmaxf(acc[r], 0.f);
    s_s[rh * 128 + o] = ps;
    __syncthreads();
    if (tid < 128) s_sf[tid] = s_s[tid] + s_s[128 + tid];
    __syncthreads();

    {
        float a = bf1[tid];
        for (int c4 = 0; c4 < 32; ++c4) {
            float4 f = *reinterpret_cast<const float4*>(&s_sf[c4 * 4]);
            a += f.x * F1t[(c4 * 4 + 0) * 256 + tid];
            a += f.y * F1t[(c4 * 4 + 1) * 256 + tid];
            a += f.z * F1t[(c4 * 4 + 2) * 256 + tid];
            a += f.w * F1t[(c4 * 4 + 3) * 256 + tid];
        }
        s_t1[tid] = fmaxf(a, 0.f);
    }
    __syncthreads();

    {
        float a = bf2[tid];
        for (int c4 = 0; c4 < 64; ++c4) {
            float4 f = *reinterpret_cast<const float4*>(&s_t1[c4 * 4]);
            a += f.x * F2t[(c4 * 4 + 0) * 256 + tid];
            a += f.y * F2t[(c4 * 4 + 1) * 256 + tid];
            a += f.z * F2t[(c4 * 4 + 2) * 256 + tid];
            a += f.w * F2t[(c4 * 4 + 3) * 256 + tid];
        }
        outp[(size_t)n * 256 + tid] = a;
    }
}

// ---------------------------------------------------------------------------
extern "C" void kernel_launch(void* const* d_in, const int* in_sizes, int n_in,
                              void* d_out, int out_size, void* d_ws, size_t ws_size,
                              hipStream_t stream)
{
    const int* pos = (const int*)d_in[0];
    const float* rt = (const float*)d_in[1];
    const float* emb = (const float*)d_in[2];
    const float* w1 = (const float*)d_in[3];
    const float* bc1 = (const float*)d_in[4];
    const float* w2 = (const float*)d_in[5];
    const float* bc2 = (const float*)d_in[6];
    const float* w3 = (const float*)d_in[7];
    const float* bc3 = (const float*)d_in[8];
    const float* wr1 = (const float*)d_in[9];
    const float* br1 = (const float*)d_in[10];
    const float* wr2 = (const float*)d_in[11];
    const float* br2 = (const float*)d_in[12];
    const float* wf1 = (const float*)d_in[13];
    const float* bf1 = (const float*)d_in[14];
    const float* wf2 = (const float*)d_in[15];
    const float* bf2 = (const float*)d_in[16];
    float* out = (float*)d_out;
    char* ws = (char*)d_ws;

    prep_weights<<<880, 256, 0, stream>>>(w1, w2, w3, wr1, wr2, wf1, wf2, ws);

    // pick largest batch chunk that fits the workspace
    int nc = 16;
    const int cands[4] = {256, 128, 64, 32};
    for (int k = 0; k < 4; ++k) {
        size_t need = B_CHUNK + (size_t)cands[k] * PERN_BYTES;
        if (need <= ws_size) { nc = cands[k]; break; }
    }

    short* W1F = (short*)(ws + B_W1F);
    short* W2F = (short*)(ws + B_W2F);
    short* W3F = (short*)(ws + B_W3F);
    float* HEAD = (float*)(ws + B_HEAD);
    float* FEAT = (float*)(ws + B_FEAT);
    short* Xc = (short*)(ws + B_CHUNK);
    short* YA = Xc + (size_t)nc * (MXY * MXY) * CIN1;
    short* YB = YA + (size_t)nc * (MXY * MXY) * 64;

    for (int n0 = 0; n0 < NB; n0 += nc) {
        build_x<<<dim3(21, nc), 256, 0, stream>>>(pos, rt, emb, Xc, n0);
        conv_mfma<16, 5, 14, 24><<<dim3(27, nc), 256, 0, stream>>>(Xc, W1F, bc1, YA);
        conv_mfma<64, 3, 18, 72><<<dim3(27, nc), 256, 0, stream>>>(YA, W2F, bc2, YB);
        conv_mfma<64, 3, 18, 72><<<dim3(27, nc), 256, 0, stream>>>(YB, W3F, bc3, YA);
        gather_mean<<<dim3(RR, nc), 64, 0, stream>>>(YA, rt, pos, FEAT, n0);
    }

    mlp_head<<<NB, 256, 0, stream>>>(FEAT, HEAD, br1, br2, bf1, bf2, out);
}